// Round 1
// baseline (1509.880 us; speedup 1.0000x reference)
//
#include <hip/hip_runtime.h>

// GraphConv: B=16, S=50000, FIN=FOUT=16, T=64, E=8M
// R1 theory: 64M memory-side 4B atomics (WRITE_SIZE==64M*4B) are the wall
// (162G atomics/s, VALU 13%, HBM 23%). Replace scatter-atomics with
// row-bucketed LDS f32 accumulation: bucket edges by row/960 (834 buckets),
// one workgroup per bucket accumulates in LDS (ds_add_f32) and writes the
// final f32 output coalesced, atomic-free. Drops outT + memset + out-transpose.
#define BNUM 16
#define NCOL 800000   // S*FIN
#define NROW 800000   // S*FOUT
#define BROWS 960     // rows per bucket (960*17*4 = 65280 B LDS accum tile)
#define NB 834        // ceil(NROW / BROWS)
#define ASTR 17       // acc row stride (odd -> spread banks)

// ---- bf16 <-> f32 helpers (bit-exact RNE) ----
__device__ __forceinline__ unsigned short f2bf(float f) {
    unsigned u = __float_as_uint(f);
    unsigned r = (u + 0x7fffu + ((u >> 16) & 1u)) >> 16;   // round-nearest-even
    return (unsigned short)r;
}
__device__ __forceinline__ float bf2f(unsigned short h) {
    return __uint_as_float(((unsigned)h) << 16);
}

// x [16][800000] f32 (b-major) -> xT [800000][16] bf16 (c-major, 32B per c)
__global__ __launch_bounds__(256) void k_transpose_x(const float* __restrict__ x,
                                                     unsigned* __restrict__ xT) {
    int c = blockIdx.x * 256 + threadIdx.x;
    if (c >= NCOL) return;
    unsigned p[8];
#pragma unroll
    for (int b = 0; b < 8; ++b) {
        float lo = x[(size_t)(2 * b)     * NCOL + c];   // coalesced per b
        float hi = x[(size_t)(2 * b + 1) * NCOL + c];
        p[b] = (unsigned)f2bf(lo) | ((unsigned)f2bf(hi) << 16);
    }
    uint4* dst = reinterpret_cast<uint4*>(xT + (size_t)c * 8);  // 32B contiguous
    dst[0] = make_uint4(p[0], p[1], p[2], p[3]);
    dst[1] = make_uint4(p[4], p[5], p[6], p[7]);
}

// ---------------- new path: counting-bucket + LDS accumulate ----------------

// Per-block LDS histogram of row buckets -> global counts (834 atomics/block).
__global__ __launch_bounds__(256) void k_hist(const int* __restrict__ rows,
                                              unsigned* __restrict__ gcount,
                                              int E, int chunk) {
    __shared__ unsigned h[NB];
    for (int i = threadIdx.x; i < NB; i += 256) h[i] = 0u;
    __syncthreads();
    int c0 = blockIdx.x * chunk;
    int c1 = min(E, c0 + chunk);
    for (int e = c0 + threadIdx.x; e < c1; e += 256) {
        int r = __builtin_nontemporal_load(rows + e);
        atomicAdd(&h[(unsigned)r / BROWS], 1u);
    }
    __syncthreads();
    for (int i = threadIdx.x; i < NB; i += 256)
        if (h[i]) atomicAdd(&gcount[i], h[i]);
}

// Exclusive scan of 834 counts (single block), init cursors.
__global__ __launch_bounds__(1024) void k_scan(const unsigned* __restrict__ gcount,
                                               unsigned* __restrict__ offs,
                                               unsigned* __restrict__ cursor) {
    __shared__ unsigned s[1024];
    int t = threadIdx.x;
    s[t] = (t < NB) ? gcount[t] : 0u;
    __syncthreads();
    for (int off = 1; off < 1024; off <<= 1) {
        unsigned v = s[t];
        if (t >= off) v += s[t - off];
        __syncthreads();
        s[t] = v;
        __syncthreads();
    }
    if (t < NB) {
        unsigned ex = t ? s[t - 1] : 0u;
        offs[t] = ex;
        cursor[t] = ex;
    }
    if (t == NB - 1) offs[NB] = s[t];
}

// Scatter edges into bucket-contiguous record arrays.
// recA = col | (type<<20)  (col<2^20, type<64);  recB = row - bucket*960.
__global__ __launch_bounds__(256) void k_place(const int* __restrict__ rows,
                                               const int* __restrict__ cols,
                                               const int* __restrict__ et,
                                               unsigned* __restrict__ cursor,
                                               unsigned* __restrict__ recA,
                                               unsigned short* __restrict__ recB,
                                               int E, int chunk) {
    __shared__ unsigned h[NB];
    __shared__ unsigned base[NB];
    __shared__ unsigned cur[NB];
    for (int i = threadIdx.x; i < NB; i += 256) { h[i] = 0u; cur[i] = 0u; }
    __syncthreads();
    int c0 = blockIdx.x * chunk;
    int c1 = min(E, c0 + chunk);
    for (int e = c0 + threadIdx.x; e < c1; e += 256) {
        int r = __builtin_nontemporal_load(rows + e);
        atomicAdd(&h[(unsigned)r / BROWS], 1u);
    }
    __syncthreads();
    for (int i = threadIdx.x; i < NB; i += 256) {
        unsigned c = h[i];
        base[i] = c ? atomicAdd(&cursor[i], c) : 0u;
    }
    __syncthreads();
    for (int e = c0 + threadIdx.x; e < c1; e += 256) {
        int r  = __builtin_nontemporal_load(rows + e);
        int cc = __builtin_nontemporal_load(cols + e);
        int t  = __builtin_nontemporal_load(et + e);
        unsigned bkt  = (unsigned)r / BROWS;
        unsigned rank = atomicAdd(&cur[bkt], 1u);
        unsigned idx  = base[bkt] + rank;
        __builtin_nontemporal_store((unsigned)cc | ((unsigned)t << 20), recA + idx);
        __builtin_nontemporal_store((unsigned short)((unsigned)r - bkt * BROWS), recB + idx);
    }
}

// One block per bucket: LDS f32 accumulate (ds_add_f32), then coalesced
// non-atomic store of the final [16][800000] f32 output slice.
// 8 lanes/edge (lane j owns batches 2j,2j+1); 2-deep pipeline for gather MLP.
__global__ __launch_bounds__(1024, 8) void k_accum(const unsigned* __restrict__ offs,
                                                   const unsigned* __restrict__ recA,
                                                   const unsigned short* __restrict__ recB,
                                                   const float* __restrict__ w,
                                                   const unsigned* __restrict__ xT,
                                                   float* __restrict__ out) {
    __shared__ float acc[BROWS * ASTR];   // 65280 B
    int b   = blockIdx.x;
    int tid = threadIdx.x;
    for (int i = tid; i < BROWS * ASTR; i += 1024) acc[i] = 0.f;
    __syncthreads();

    int beg = (int)offs[b];
    int end = (int)offs[b + 1];
    int g = tid >> 3;        // edge group 0..127
    int j = tid & 7;         // batch pair
    for (int i = beg + g; i < end; i += 256) {
        int i1 = i + 128;
        bool h1 = i1 < end;
        unsigned a0 = __builtin_nontemporal_load(recA + i);
        unsigned r0 = __builtin_nontemporal_load(recB + i);
        unsigned a1 = 0u, r1 = 0u;
        if (h1) {
            a1 = __builtin_nontemporal_load(recA + i1);
            r1 = __builtin_nontemporal_load(recB + i1);
        }
        unsigned c0 = a0 & 0xFFFFFu;
        unsigned t0 = a0 >> 20;
        unsigned px0 = xT[(size_t)c0 * 8 + j];         // cached gather (hot path)
        float   wt0 = w[t0];                            // 256B table, L1-hot
        unsigned px1 = 0u; float wt1 = 0.f; unsigned rr1 = 0u;
        if (h1) {
            unsigned c1v = a1 & 0xFFFFFu;
            unsigned t1  = a1 >> 20;
            px1 = xT[(size_t)c1v * 8 + j];
            wt1 = w[t1];
            rr1 = r1;
        }
        float* p0 = &acc[r0 * ASTR + 2 * j];
        atomicAdd(p0,     wt0 * bf2f((unsigned short)(px0 & 0xffffu)));
        atomicAdd(p0 + 1, wt0 * bf2f((unsigned short)(px0 >> 16)));
        if (h1) {
            float* p1 = &acc[rr1 * ASTR + 2 * j];
            atomicAdd(p1,     wt1 * bf2f((unsigned short)(px1 & 0xffffu)));
            atomicAdd(p1 + 1, wt1 * bf2f((unsigned short)(px1 >> 16)));
        }
    }
    __syncthreads();

    int r0b = b * BROWS;
    int m = min(BROWS, NROW - r0b);
    if (tid < m) {
#pragma unroll
        for (int k = 0; k < BNUM; ++k)
            __builtin_nontemporal_store(acc[tid * ASTR + k],
                                        out + (size_t)k * NROW + r0b + tid);
    }
}

// ---------------- fallback path (old atomic scatter, needs only 51.2MB) ----

__global__ __launch_bounds__(256) void k_scatter(const int* __restrict__ rows,
                                                 const int* __restrict__ cols,
                                                 const int* __restrict__ et,
                                                 const float* __restrict__ w,
                                                 const unsigned* __restrict__ xT,
                                                 unsigned short* __restrict__ outT,
                                                 int E) {
    long long tid = (long long)blockIdx.x * 256 + threadIdx.x;
    long long e = tid >> 3;
    if (e >= E) return;
    int j = (int)(tid & 7);
    int r = __builtin_nontemporal_load(rows + e);
    int c = __builtin_nontemporal_load(cols + e);
    int t = __builtin_nontemporal_load(et + e);
    float wt = w[t];
    unsigned px = xT[(size_t)c * 8 + j];
    float x0 = bf2f((unsigned short)(px & 0xffffu));
    float x1 = bf2f((unsigned short)(px >> 16));
    unsigned short b0 = f2bf(wt * x0);
    unsigned short b1 = f2bf(wt * x1);
    unsigned data = (unsigned)b0 | ((unsigned)b1 << 16);
    unsigned short* dst = outT + ((size_t)r * 16 + 2 * j);
    asm volatile("global_atomic_pk_add_bf16 %0, %1, off"
                 :: "v"(dst), "v"(data) : "memory");
}

__global__ __launch_bounds__(256) void k_transpose_out(const unsigned* __restrict__ outT,
                                                       float* __restrict__ out) {
    int r = blockIdx.x * 256 + threadIdx.x;
    if (r >= NROW) return;
    const uint4* src = reinterpret_cast<const uint4*>(outT + (size_t)r * 8);
    uint4 v0 = src[0], v1 = src[1];
    unsigned p[8] = {v0.x, v0.y, v0.z, v0.w, v1.x, v1.y, v1.z, v1.w};
#pragma unroll
    for (int b = 0; b < 8; ++b) {
        out[(size_t)(2 * b)     * NROW + r] = bf2f((unsigned short)(p[b] & 0xffffu));
        out[(size_t)(2 * b + 1) * NROW + r] = bf2f((unsigned short)(p[b] >> 16));
    }
}

extern "C" void kernel_launch(void* const* d_in, const int* in_sizes, int n_in,
                              void* d_out, int out_size, void* d_ws, size_t ws_size,
                              hipStream_t stream) {
    const float* x    = (const float*)d_in[0];
    const float* w    = (const float*)d_in[1];
    const int*   rows = (const int*)d_in[2];
    const int*   cols = (const int*)d_in[3];
    const int*   et   = (const int*)d_in[4];
    const int    E    = in_sizes[2];

    float* out = (float*)d_out;

    // ws layout (new path): xT bf16 [25.6MB] | recA u32 [4E] | recB u16 [2E] | aux
    size_t xT_b     = (size_t)NCOL * 8 * 4;           // 25,600,000
    size_t recA_off = xT_b;
    size_t recB_off = recA_off + (size_t)E * 4;
    size_t aux_off  = (recB_off + (size_t)E * 2 + 15) & ~(size_t)15;
    size_t needed   = aux_off + (size_t)(NB + (NB + 1) + NB) * 4;

    unsigned* xT = (unsigned*)d_ws;

    if (ws_size >= needed) {
        // ---- bucketed LDS-accumulation path (no global atomics on output) ----
        unsigned*       recA   = (unsigned*)((char*)d_ws + recA_off);
        unsigned short* recB   = (unsigned short*)((char*)d_ws + recB_off);
        unsigned*       gcount = (unsigned*)((char*)d_ws + aux_off);
        unsigned*       offs   = gcount + NB;
        unsigned*       cursor = offs + NB + 1;

        hipMemsetAsync(gcount, 0, (size_t)NB * 4, stream);
        k_transpose_x<<<NCOL / 256, 256, 0, stream>>>(x, xT);

        int chunk_h = (E + 1023) / 1024;
        k_hist<<<1024, 256, 0, stream>>>(rows, gcount, E, chunk_h);
        k_scan<<<1, 1024, 0, stream>>>(gcount, offs, cursor);
        int chunk_p = (E + 511) / 512;
        k_place<<<512, 256, 0, stream>>>(rows, cols, et, cursor, recA, recB, E, chunk_p);
        k_accum<<<NB, 1024, 0, stream>>>(offs, recA, recB, w, xT, out);
    } else {
        // ---- fallback: previous pk_add_bf16 atomic scatter (51.2MB ws) ----
        unsigned short* outT = (unsigned short*)d_ws;
        unsigned*       xT2  = (unsigned*)((char*)d_ws + (size_t)NROW * BNUM * 2);

        hipMemsetAsync(outT, 0, (size_t)NROW * BNUM * 2, stream);
        k_transpose_x<<<NCOL / 256, 256, 0, stream>>>(x, xT2);

        long long total = (long long)E * 8;
        int blocks = (int)((total + 255) / 256);
        k_scatter<<<blocks, 256, 0, stream>>>(rows, cols, et, w, xT2, outT, E);
        k_transpose_out<<<NROW / 256, 256, 0, stream>>>((const unsigned*)outT, out);
    }
}

// Round 2
// 338.328 us; speedup vs baseline: 4.4628x; 4.4628x over previous
//
#include <hip/hip_runtime.h>

// GraphConv: B=16, S=50000, FIN=FOUT=16, T=64, E=8M
// R2: R1 post-mortem — k_accum's 128M fine-grained LDS atomics serialized
// (793us, all pipes idle) and k_place's 4B random global scatter (~650us).
// New: coalesced multisplit place (register-held chunk, LDS local sort,
// run-contiguous flush) + pull-style accumulate (LDS counting sort per
// bucket, per-thread register f32 accumulators, zero output atomics).
#define BNUM 16
#define NCOL 800000   // S*FIN
#define NROW 800000   // S*FOUT
#define BROWS 960     // rows per bucket
#define NB 834        // ceil(NROW / BROWS)
#define CAP 10240     // srt capacity per bucket (mean 9592, +6.6 sigma)
#define PR 8192       // edges per place block
#define PT 512        // place block threads (16 edges/thread)

#define WG_ADD(p, v) __hip_atomic_fetch_add((p), (v), __ATOMIC_RELAXED, __HIP_MEMORY_SCOPE_WORKGROUP)

// ---- bf16 <-> f32 helpers (bit-exact RNE) ----
__device__ __forceinline__ unsigned short f2bf(float f) {
    unsigned u = __float_as_uint(f);
    unsigned r = (u + 0x7fffu + ((u >> 16) & 1u)) >> 16;   // round-nearest-even
    return (unsigned short)r;
}
__device__ __forceinline__ float bf2f(unsigned short h) {
    return __uint_as_float(((unsigned)h) << 16);
}

// x [16][800000] f32 (b-major) -> xT [800000][16] bf16 (c-major, 32B per c)
__global__ __launch_bounds__(256) void k_transpose_x(const float* __restrict__ x,
                                                     unsigned* __restrict__ xT) {
    int c = blockIdx.x * 256 + threadIdx.x;
    if (c >= NCOL) return;
    unsigned p[8];
#pragma unroll
    for (int b = 0; b < 8; ++b) {
        float lo = x[(size_t)(2 * b)     * NCOL + c];   // coalesced per b
        float hi = x[(size_t)(2 * b + 1) * NCOL + c];
        p[b] = (unsigned)f2bf(lo) | ((unsigned)f2bf(hi) << 16);
    }
    uint4* dst = reinterpret_cast<uint4*>(xT + (size_t)c * 8);  // 32B contiguous
    dst[0] = make_uint4(p[0], p[1], p[2], p[3]);
    dst[1] = make_uint4(p[4], p[5], p[6], p[7]);
}

// Per-block LDS histogram of row buckets -> global counts.
__global__ __launch_bounds__(256) void k_hist(const int* __restrict__ rows,
                                              unsigned* __restrict__ gcount,
                                              int E, int chunk) {
    __shared__ unsigned h[NB];
    for (int i = threadIdx.x; i < NB; i += 256) h[i] = 0u;
    __syncthreads();
    int c0 = blockIdx.x * chunk;
    int c1 = min(E, c0 + chunk);
    for (int e = c0 + threadIdx.x; e < c1; e += 256) {
        int r = __builtin_nontemporal_load(rows + e);
        WG_ADD(&h[(unsigned)r / BROWS], 1u);
    }
    __syncthreads();
    for (int i = threadIdx.x; i < NB; i += 256)
        if (h[i]) atomicAdd(&gcount[i], h[i]);
}

// Exclusive scan of 834 counts (single block), init cursors (= place bases).
__global__ __launch_bounds__(1024) void k_scan(const unsigned* __restrict__ gcount,
                                               unsigned* __restrict__ offs,
                                               unsigned* __restrict__ cursor) {
    __shared__ unsigned s[1024];
    int t = threadIdx.x;
    s[t] = (t < NB) ? gcount[t] : 0u;
    __syncthreads();
    for (int off = 1; off < 1024; off <<= 1) {
        unsigned v = s[t];
        if (t >= off) v += s[t - off];
        __syncthreads();
        s[t] = v;
        __syncthreads();
    }
    if (t < NB) {
        unsigned ex = t ? s[t - 1] : 0u;
        offs[t] = ex;
        cursor[t] = ex;
    }
    if (t == NB - 1) offs[NB] = s[t];
}

// Coalescing multisplit: each block takes PR edges (held in registers),
// locally sorts by bucket in LDS, reserves one global range per bucket,
// flushes bucket-contiguous runs.  recA = col|type<<20, recB = local row.
__global__ __launch_bounds__(PT) void k_place(const int* __restrict__ rows,
                                              const int* __restrict__ cols,
                                              const int* __restrict__ et,
                                              unsigned* __restrict__ cursor,
                                              unsigned* __restrict__ recA,
                                              unsigned short* __restrict__ recB,
                                              int E) {
    __shared__ unsigned cnt[NB];      // hist, then reused as place cursor
    __shared__ unsigned lofs[NB];     // local exclusive offsets
    __shared__ unsigned gbase[NB];    // reserved global bases
    __shared__ unsigned srtA[PR];     // col|type, bucket-sorted
    __shared__ unsigned srtR[PR];     // (bucket<<10) | lrow
    __shared__ unsigned wsum[8];

    int t  = threadIdx.x;
    int c0 = blockIdx.x * PR;
    int c1 = min(E, c0 + PR);
    int tot = c1 - c0;

    for (int i = t; i < NB; i += PT) cnt[i] = 0u;
    __syncthreads();

    // load 16 edges/thread into registers (statically indexed)
    unsigned er[16], ec[16];
#pragma unroll
    for (int k = 0; k < 16; ++k) {
        int e = c0 + k * PT + t;
        if (e < c1) {
            int r  = __builtin_nontemporal_load(rows + e);
            int c  = __builtin_nontemporal_load(cols + e);
            int ty = __builtin_nontemporal_load(et + e);
            er[k] = (unsigned)r;
            ec[k] = (unsigned)c | ((unsigned)ty << 20);
        } else {
            er[k] = 0xFFFFFFFFu;
            ec[k] = 0u;
        }
    }
    // local hist
#pragma unroll
    for (int k = 0; k < 16; ++k)
        if (er[k] != 0xFFFFFFFFu) WG_ADD(&cnt[er[k] / BROWS], 1u);
    __syncthreads();

    // exclusive scan of cnt[834] (2 entries/thread, wave shuffle scan)
    {
        unsigned a0 = (2 * t     < NB) ? cnt[2 * t]     : 0u;
        unsigned a1 = (2 * t + 1 < NB) ? cnt[2 * t + 1] : 0u;
        unsigned ts = a0 + a1;
        unsigned incl = ts;
        for (int off = 1; off < 64; off <<= 1) {
            unsigned n = __shfl_up(incl, off, 64);
            if ((t & 63) >= off) incl += n;
        }
        if ((t & 63) == 63) wsum[t >> 6] = incl;
        __syncthreads();
        unsigned pre = 0;
        for (int k2 = 0; k2 < (t >> 6); ++k2) pre += wsum[k2];
        unsigned ex = pre + incl - ts;
        if (2 * t     < NB) lofs[2 * t]     = ex;
        if (2 * t + 1 < NB) lofs[2 * t + 1] = ex + a0;
    }
    __syncthreads();

    // reserve global ranges (one atomic per non-empty bucket)
    for (int i = t; i < NB; i += PT) {
        unsigned c = cnt[i];
        gbase[i] = c ? atomicAdd(&cursor[i], c) : 0u;
    }
    __syncthreads();
    for (int i = t; i < NB; i += PT) cnt[i] = 0u;   // reuse as rank cursor
    __syncthreads();

    // ranked place into LDS (bucket-sorted order)
#pragma unroll
    for (int k = 0; k < 16; ++k) {
        if (er[k] == 0xFFFFFFFFu) continue;
        unsigned b  = er[k] / BROWS;
        unsigned lr = er[k] - b * BROWS;
        unsigned rk = WG_ADD(&cnt[b], 1u);
        unsigned j  = lofs[b] + rk;
        srtA[j] = ec[k];
        srtR[j] = (b << 10) | lr;
    }
    __syncthreads();

    // flush: consecutive j within a bucket run -> consecutive global dst
    for (int j = t; j < tot; j += PT) {
        unsigned rr = srtR[j];
        unsigned b  = rr >> 10;
        unsigned dst = gbase[b] + ((unsigned)j - lofs[b]);
        __builtin_nontemporal_store(srtA[j], recA + dst);
        __builtin_nontemporal_store((unsigned short)(rr & 1023u), recB + dst);
    }
}

__device__ __forceinline__ void fma8(float* a, float wt, uint4 v, int base) {
    a[base + 0] += wt * bf2f((unsigned short)(v.x & 0xffffu));
    a[base + 1] += wt * bf2f((unsigned short)(v.x >> 16));
    a[base + 2] += wt * bf2f((unsigned short)(v.y & 0xffffu));
    a[base + 3] += wt * bf2f((unsigned short)(v.y >> 16));
    a[base + 4] += wt * bf2f((unsigned short)(v.z & 0xffffu));
    a[base + 5] += wt * bf2f((unsigned short)(v.z >> 16));
    a[base + 6] += wt * bf2f((unsigned short)(v.w & 0xffffu));
    a[base + 7] += wt * bf2f((unsigned short)(v.w >> 16));
}

// One block per bucket: LDS counting sort by local row, then each thread
// owns one row -> register f32 accumulate (no atomics), coalesced store.
__global__ __launch_bounds__(1024) void k_pull(const unsigned* __restrict__ offs,
                                               const unsigned* __restrict__ recA,
                                               const unsigned short* __restrict__ recB,
                                               const float* __restrict__ w,
                                               const unsigned* __restrict__ xT,
                                               float* __restrict__ out) {
    __shared__ unsigned hist[BROWS];
    __shared__ unsigned ptr_[BROWS + 1];
    __shared__ unsigned cur[BROWS];
    __shared__ unsigned srt[CAP];
    __shared__ unsigned wsum[16];

    int b   = blockIdx.x;
    int tid = threadIdx.x;
    int beg = (int)offs[b];
    int end = (int)offs[b + 1];
    int n   = min(end - beg, CAP);

    for (int i = tid; i < BROWS; i += 1024) { hist[i] = 0u; cur[i] = 0u; }
    __syncthreads();

    for (int i = tid; i < n; i += 1024)
        WG_ADD(&hist[recB[beg + i]], 1u);
    __syncthreads();

    // exclusive scan of hist[960] -> ptr_, ptr_[960] = n
    if (tid < BROWS) {
        unsigned v = hist[tid];
        unsigned incl = v;
        for (int off = 1; off < 64; off <<= 1) {
            unsigned m = __shfl_up(incl, off, 64);
            if ((tid & 63) >= off) incl += m;
        }
        if ((tid & 63) == 63) wsum[tid >> 6] = incl;
    }
    __syncthreads();
    if (tid < BROWS) {
        unsigned pre = 0;
        for (int k2 = 0; k2 < (tid >> 6); ++k2) pre += wsum[k2];
        unsigned v = hist[tid];
        unsigned incl = v;
        for (int off = 1; off < 64; off <<= 1) {
            unsigned m = __shfl_up(incl, off, 64);
            if ((tid & 63) >= off) incl += m;
        }
        ptr_[tid] = pre + incl - v;
        if (tid == BROWS - 1) ptr_[BROWS] = pre + incl;
    }
    __syncthreads();

    // counting-sort recs by local row into LDS
    for (int i = tid; i < n; i += 1024) {
        unsigned lr = recB[beg + i];
        unsigned rk = WG_ADD(&cur[lr], 1u);
        srt[ptr_[lr] + rk] = recA[beg + i];
    }
    __syncthreads();

    // pull: thread t owns row t; register accumulate; 2-deep gather pipeline
    if (tid < BROWS) {
        int p0 = (int)ptr_[tid];
        int p1 = (int)ptr_[tid + 1];
        float a[16];
#pragma unroll
        for (int k = 0; k < 16; ++k) a[k] = 0.f;

        uint4 lo = make_uint4(0, 0, 0, 0), hi = lo;
        unsigned u = 0u;
        int p = p0;
        if (p < p1) {
            u = srt[p];
            const uint4* q = reinterpret_cast<const uint4*>(xT + (size_t)(u & 0xFFFFFu) * 8);
            lo = q[0]; hi = q[1];
        }
        while (p < p1) {
            int pn = p + 1;
            unsigned un = 0u;
            uint4 lon = make_uint4(0, 0, 0, 0), hin = lon;
            if (pn < p1) {
                un = srt[pn];
                const uint4* qn = reinterpret_cast<const uint4*>(xT + (size_t)(un & 0xFFFFFu) * 8);
                lon = qn[0]; hin = qn[1];
            }
            float wt = w[u >> 20];
            fma8(a, wt, lo, 0);
            fma8(a, wt, hi, 8);
            u = un; lo = lon; hi = hin; p = pn;
        }

        int r = b * BROWS + tid;
        if (r < NROW) {
#pragma unroll
            for (int k = 0; k < 16; ++k)
                __builtin_nontemporal_store(a[k], out + (size_t)k * NROW + r);
        }
    }

    // statistically-never overflow path (bucket > CAP): atomic add on top
    if (end - beg > CAP) {
        __syncthreads();
        for (int i = beg + CAP + tid; i < end; i += 1024) {
            unsigned uu = recA[i];
            unsigned lr = recB[i];
            int r = b * BROWS + (int)lr;
            float wt = w[uu >> 20];
            const uint4* q = reinterpret_cast<const uint4*>(xT + (size_t)(uu & 0xFFFFFu) * 8);
            uint4 vlo = q[0], vhi = q[1];
            float tmp[16];
#pragma unroll
            for (int k = 0; k < 16; ++k) tmp[k] = 0.f;
            fma8(tmp, wt, vlo, 0);
            fma8(tmp, wt, vhi, 8);
#pragma unroll
            for (int k = 0; k < 16; ++k)
                atomicAdd(out + (size_t)k * NROW + r, tmp[k]);
        }
    }
}

// ---------------- fallback path (old atomic scatter, needs only 51.2MB) ----

__global__ __launch_bounds__(256) void k_scatter(const int* __restrict__ rows,
                                                 const int* __restrict__ cols,
                                                 const int* __restrict__ et,
                                                 const float* __restrict__ w,
                                                 const unsigned* __restrict__ xT,
                                                 unsigned short* __restrict__ outT,
                                                 int E) {
    long long tid = (long long)blockIdx.x * 256 + threadIdx.x;
    long long e = tid >> 3;
    if (e >= E) return;
    int j = (int)(tid & 7);
    int r = __builtin_nontemporal_load(rows + e);
    int c = __builtin_nontemporal_load(cols + e);
    int t = __builtin_nontemporal_load(et + e);
    float wt = w[t];
    unsigned px = xT[(size_t)c * 8 + j];
    float x0 = bf2f((unsigned short)(px & 0xffffu));
    float x1 = bf2f((unsigned short)(px >> 16));
    unsigned short b0 = f2bf(wt * x0);
    unsigned short b1 = f2bf(wt * x1);
    unsigned data = (unsigned)b0 | ((unsigned)b1 << 16);
    unsigned short* dst = outT + ((size_t)r * 16 + 2 * j);
    asm volatile("global_atomic_pk_add_bf16 %0, %1, off"
                 :: "v"(dst), "v"(data) : "memory");
}

__global__ __launch_bounds__(256) void k_transpose_out(const unsigned* __restrict__ outT,
                                                       float* __restrict__ out) {
    int r = blockIdx.x * 256 + threadIdx.x;
    if (r >= NROW) return;
    const uint4* src = reinterpret_cast<const uint4*>(outT + (size_t)r * 8);
    uint4 v0 = src[0], v1 = src[1];
    unsigned p[8] = {v0.x, v0.y, v0.z, v0.w, v1.x, v1.y, v1.z, v1.w};
#pragma unroll
    for (int b = 0; b < 8; ++b) {
        out[(size_t)(2 * b)     * NROW + r] = bf2f((unsigned short)(p[b] & 0xffffu));
        out[(size_t)(2 * b + 1) * NROW + r] = bf2f((unsigned short)(p[b] >> 16));
    }
}

extern "C" void kernel_launch(void* const* d_in, const int* in_sizes, int n_in,
                              void* d_out, int out_size, void* d_ws, size_t ws_size,
                              hipStream_t stream) {
    const float* x    = (const float*)d_in[0];
    const float* w    = (const float*)d_in[1];
    const int*   rows = (const int*)d_in[2];
    const int*   cols = (const int*)d_in[3];
    const int*   et   = (const int*)d_in[4];
    const int    E    = in_sizes[2];

    float* out = (float*)d_out;

    // ws layout: xT bf16 [25.6MB] | recA u32 [4E] | recB u16 [2E] | aux
    size_t xT_b     = (size_t)NCOL * 8 * 4;           // 25,600,000
    size_t recA_off = xT_b;
    size_t recB_off = recA_off + (size_t)E * 4;
    size_t aux_off  = (recB_off + (size_t)E * 2 + 15) & ~(size_t)15;
    size_t needed   = aux_off + (size_t)(NB + (NB + 1) + NB) * 4;

    unsigned* xT = (unsigned*)d_ws;

    if (ws_size >= needed) {
        unsigned*       recA   = (unsigned*)((char*)d_ws + recA_off);
        unsigned short* recB   = (unsigned short*)((char*)d_ws + recB_off);
        unsigned*       gcount = (unsigned*)((char*)d_ws + aux_off);
        unsigned*       offs   = gcount + NB;
        unsigned*       cursor = offs + NB + 1;

        hipMemsetAsync(gcount, 0, (size_t)NB * 4, stream);
        k_transpose_x<<<NCOL / 256, 256, 0, stream>>>(x, xT);

        int chunk_h = (E + 1023) / 1024;
        k_hist<<<1024, 256, 0, stream>>>(rows, gcount, E, chunk_h);
        k_scan<<<1, 1024, 0, stream>>>(gcount, offs, cursor);
        int pblocks = (E + PR - 1) / PR;
        k_place<<<pblocks, PT, 0, stream>>>(rows, cols, et, cursor, recA, recB, E);
        k_pull<<<NB, 1024, 0, stream>>>(offs, recA, recB, w, xT, out);
    } else {
        // fallback: pk_add_bf16 atomic scatter (51.2MB ws)
        unsigned short* outT = (unsigned short*)d_ws;
        unsigned*       xT2  = (unsigned*)((char*)d_ws + (size_t)NROW * BNUM * 2);

        hipMemsetAsync(outT, 0, (size_t)NROW * BNUM * 2, stream);
        k_transpose_x<<<NCOL / 256, 256, 0, stream>>>(x, xT2);

        long long total = (long long)E * 8;
        int blocks = (int)((total + 255) / 256);
        k_scatter<<<blocks, 256, 0, stream>>>(rows, cols, et, w, xT2, outT, E);
        k_transpose_out<<<NROW / 256, 256, 0, stream>>>((const unsigned*)outT, out);
    }
}